// Round 5
// baseline (199.778 us; speedup 1.0000x reference)
//
#include <hip/hip_runtime.h>

#define BATCH 32
#define IMG 512
#define CH 3
#define GOUT 64
#define ROWB (IMG*CH)   // 1536 floats per image row

typedef __attribute__((ext_vector_type(8))) short  short8;   // 8 bf16 = 4 VGPRs
typedef __attribute__((ext_vector_type(4))) float  floatx4;  // MFMA 16x16 acc

__device__ __forceinline__ unsigned short f2bf(float x) {
    // round-to-nearest-even fp32 -> bf16 (finite inputs only)
    unsigned u = __builtin_bit_cast(unsigned, x);
    u += 0x7FFFu + ((u >> 16) & 1u);
    return (unsigned short)(u >> 16);
}

// ---------------------------------------------------------------------------
// Kernel 1: Gaussian filterbank masks, TRANSPOSED bf16: AyT[b][H][h],
// AxT[b][W][w] (k-contiguous). One wave per (b, axis, r).
// ---------------------------------------------------------------------------
__global__ __launch_bounds__(64) void mask_kernel(const float* __restrict__ tp,
                                                  unsigned short* __restrict__ AyT,
                                                  unsigned short* __restrict__ AxT) {
    int blk  = blockIdx.x;
    int r    = blk & 63;
    int axis = (blk >> 6) & 1;
    int b    = blk >> 7;

    const float* p = tp + b*6 + (axis ? 3 : 0);
    float u = p[0], s = p[1], d = p[2];
    float centre = u + (float)r * d;
    float inv_s  = 1.0f / s;

    int lane = threadIdx.x;
    float e[8];
    float sum = 0.0f;
    #pragma unroll
    for (int i = 0; i < 8; ++i) {
        float z = ((float)(i*64 + lane) - centre) * inv_s;
        e[i] = __expf(-0.5f * z * z);
        sum += e[i];
    }
    #pragma unroll
    for (int m = 1; m < 64; m <<= 1)
        sum += __shfl_xor(sum, m, 64);
    float inv_sum = 1.0f / (sum + 1e-8f);

    unsigned short* dst = (axis ? AxT : AyT) + ((size_t)b*GOUT + r) * IMG;
    #pragma unroll
    for (int i = 0; i < 8; ++i)
        dst[i*64 + lane] = f2bf(e[i] * inv_sum);
}

// ---------------------------------------------------------------------------
// Kernel 2: g[b][c][H][w] = sum_h Ay[b,h,H] * img[b,h,w,c]   (planar fp32)
// LDS-staged MFMA GEMM. Round-4 lesson: per-fragment GLOBAL gathers (16-seg
// A-loads, 8x strided B-dwords) are latency-bound -> 60 us at 8% VALU.
// Here: bulk coalesced dwordx4 -> ds_write_b128 staging; fragments come from
// LDS (predictable ~6-12 cyc). LDS traffic ~830 cyc/chunk/CU vs HBM staging
// phase ~4800 cyc -> HBM-bound (~16 us floor for the 100 MB img).
// Block: 64H x 128wc tile, BK=64, 4 waves (each 2 n-tiles), 8 K-chunks.
// Grid 32*12 = 384 blocks. LDS 42 KB.
// ---------------------------------------------------------------------------
__global__ __launch_bounds__(256) void stage1_kernel(const float* __restrict__ img,
                                                     const unsigned short* __restrict__ AyT,
                                                     float* __restrict__ gP) {
    __shared__ float          Bs[64][132];  // img tile fp32, +4 pad (16B-aligned rows)
    __shared__ unsigned short As[64][72];   // Ay tile bf16, +8 pad (16B-aligned rows)

    int tile = blockIdx.x % 12;
    int b    = blockIdx.x / 12;
    int wc0  = tile * 128;
    int tid  = threadIdx.x;
    int wave = tid >> 6;
    int lane = tid & 63;
    int n16  = lane & 15;
    int q    = lane >> 4;

    floatx4 acc[4][2];
    #pragma unroll
    for (int mt = 0; mt < 4; ++mt)
        #pragma unroll
        for (int nt = 0; nt < 2; ++nt)
            acc[mt][nt] = (floatx4){0.f, 0.f, 0.f, 0.f};

    const float*          imb = img + (size_t)b * IMG * ROWB + wc0;
    const unsigned short* ayb = AyT + (size_t)b * GOUT * IMG;

    for (int h0 = 0; h0 < IMG; h0 += 64) {
        // --- stage Bs: 64 rows x 512 B, coalesced dwordx4 (8 per thread) ---
        #pragma unroll
        for (int i = 0; i < 8; ++i) {
            int p  = tid + i*256;
            int r  = p >> 5;          // 0..63
            int cg = p & 31;          // float4 within row
            float4 v = *(const float4*)(imb + (size_t)(h0 + r) * ROWB + cg*4);
            *(float4*)&Bs[r][cg*4] = v;
        }
        // --- stage As: 64 rows x 128 B bf16 (2 x 16B per thread) ---
        #pragma unroll
        for (int i = 0; i < 2; ++i) {
            int p    = tid + i*256;
            int r    = p >> 3;        // 0..63
            int koff = (p & 7) * 8;   // bf16 elems
            uint4 v = *(const uint4*)(ayb + (size_t)r * IMG + h0 + koff);
            *(uint4*)&As[r][koff] = v;
        }
        __syncthreads();

        #pragma unroll
        for (int s = 0; s < 2; ++s) {
            short8 af[4];
            #pragma unroll
            for (int mt = 0; mt < 4; ++mt)
                af[mt] = *(const short8*)&As[mt*16 + n16][s*32 + q*8];
            #pragma unroll
            for (int nt = 0; nt < 2; ++nt) {
                short8 bf;
                #pragma unroll
                for (int j = 0; j < 8; ++j)
                    bf[j] = (short)f2bf(Bs[s*32 + q*8 + j][wave*32 + nt*16 + n16]);
                #pragma unroll
                for (int mt = 0; mt < 4; ++mt)
                    acc[mt][nt] = __builtin_amdgcn_mfma_f32_16x16x32_bf16(
                        af[mt], bf, acc[mt][nt], 0, 0, 0);
            }
        }
        __syncthreads();
    }

    // Epilogue: D col = lane&15 -> wc, row = q*4+reg -> H (round-4 verified).
    #pragma unroll
    for (int nt = 0; nt < 2; ++nt) {
        int wc = wc0 + wave*32 + nt*16 + n16;
        int c = wc % 3, w = wc / 3;
        float* gb = gP + ((size_t)(b*CH + c) * GOUT) * IMG + w;
        #pragma unroll
        for (int mt = 0; mt < 4; ++mt)
            #pragma unroll
            for (int reg = 0; reg < 4; ++reg)
                gb[(size_t)(mt*16 + q*4 + reg) * IMG] = acc[mt][nt][reg];
    }
}

// ---------------------------------------------------------------------------
// Kernel 3: out[b,H,W,c] += sum_{w part} g[b,c,H,w] * Ax[b,w,W]
// bf16 MFMA; grid (b,c,part)=384 blocks; K-split 4, fp32 atomicAdd into
// zeroed d_out. A-frag now 2 x float4 (was 8 scalar loads).
// ---------------------------------------------------------------------------
__global__ __launch_bounds__(256) void stage2_kernel(const float* __restrict__ gP,
                                                     const unsigned short* __restrict__ AxT,
                                                     float* __restrict__ out) {
    int blk  = blockIdx.x;
    int part = blk & 3;
    int bc   = blk >> 2;
    int c    = bc % 3;
    int b    = bc / 3;
    int tid  = threadIdx.x;
    int wm   = tid >> 6;
    int lane = tid & 63;
    int n16  = lane & 15;
    int q    = lane >> 4;

    floatx4 acc[4];
    #pragma unroll
    for (int nt = 0; nt < 4; ++nt) acc[nt] = (floatx4){0.f, 0.f, 0.f, 0.f};

    const float*          ga  = gP  + ((size_t)(b*CH + c) * GOUT + wm*16 + n16) * IMG;
    const unsigned short* axb = AxT + ((size_t)b*GOUT + n16) * IMG;

    #pragma unroll
    for (int cc = 0; cc < 4; ++cc) {
        int w0 = part*128 + cc*32;
        const float* ap = ga + w0 + q*8;
        float4 a0 = *(const float4*)ap;
        float4 a1 = *(const float4*)(ap + 4);
        short8 af;
        af[0] = (short)f2bf(a0.x); af[1] = (short)f2bf(a0.y);
        af[2] = (short)f2bf(a0.z); af[3] = (short)f2bf(a0.w);
        af[4] = (short)f2bf(a1.x); af[5] = (short)f2bf(a1.y);
        af[6] = (short)f2bf(a1.z); af[7] = (short)f2bf(a1.w);

        #pragma unroll
        for (int nt = 0; nt < 4; ++nt) {
            short8 bf = *(const short8*)(axb + (size_t)nt*16*IMG + w0 + q*8);
            acc[nt] = __builtin_amdgcn_mfma_f32_16x16x32_bf16(af, bf, acc[nt], 0, 0, 0);
        }
    }

    #pragma unroll
    for (int nt = 0; nt < 4; ++nt) {
        int W = nt*16 + n16;
        #pragma unroll
        for (int reg = 0; reg < 4; ++reg) {
            int H = wm*16 + q*4 + reg;
            atomicAdd(out + (((size_t)b*GOUT + H) * GOUT + W) * CH + c, acc[nt][reg]);
        }
    }
}

// ---------------------------------------------------------------------------
// Workspace: AyT 2 MB | AxT 2 MB | gP 12.6 MB.
// ---------------------------------------------------------------------------
extern "C" void kernel_launch(void* const* d_in, const int* in_sizes, int n_in,
                              void* d_out, int out_size, void* d_ws, size_t ws_size,
                              hipStream_t stream) {
    const float* img = (const float*)d_in[0];
    const float* tp  = (const float*)d_in[1];
    float* out = (float*)d_out;

    unsigned short* AyT = (unsigned short*)d_ws;
    unsigned short* AxT = AyT + (size_t)BATCH * GOUT * IMG;
    float*          gP  = (float*)(AxT + (size_t)BATCH * GOUT * IMG);

    hipMemsetAsync(d_out, 0, (size_t)out_size * sizeof(float), stream);
    mask_kernel  <<<BATCH * 2 * GOUT,  64, 0, stream>>>(tp, AyT, AxT);
    stage1_kernel<<<BATCH * 12,       256, 0, stream>>>(img, AyT, gP);
    stage2_kernel<<<BATCH * CH * 4,   256, 0, stream>>>(gP, AxT, out);
}

// Round 6
// 185.935 us; speedup vs baseline: 1.0745x; 1.0745x over previous
//
#include <hip/hip_runtime.h>
#include <stdint.h>

#define BATCH 32
#define IMG 512
#define CH 3
#define GOUT 64
#define ROWB (IMG*CH)   // 1536 floats per image row
#define GP   ((size_t)BATCH*CH*GOUT*IMG)   // one K-split partial of planar g

typedef __attribute__((ext_vector_type(8))) short  short8;   // 8 bf16 = 4 VGPRs
typedef __attribute__((ext_vector_type(4))) float  floatx4;  // MFMA 16x16 acc

__device__ __forceinline__ unsigned short f2bf(float x) {
    unsigned u = __builtin_bit_cast(unsigned, x);
    u += 0x7FFFu + ((u >> 16) & 1u);
    return (unsigned short)(u >> 16);
}

// CK-style async global->LDS 16B copy. LDS dest must be wave-uniform base +
// lane*16 (caller guarantees via layout). Flat->as3 via uintptr truncation
// keeps the LDS offset (shared aperture holds offset in low bits).
typedef __attribute__((address_space(3))) unsigned int  lds_u32;
typedef __attribute__((address_space(1))) const unsigned int g_u32;
__device__ __forceinline__ void async16(const void* g, void* l) {
    __builtin_amdgcn_global_load_lds((g_u32*)(uintptr_t)g,
                                     (lds_u32*)(uintptr_t)l, 16, 0, 0);
}

// ---------------------------------------------------------------------------
// Kernel 1: Gaussian filterbank masks, TRANSPOSED bf16: AyT[b][H][h],
// AxT[b][W][w] (k-contiguous). One wave per (b, axis, r).
// ---------------------------------------------------------------------------
__global__ __launch_bounds__(64) void mask_kernel(const float* __restrict__ tp,
                                                  unsigned short* __restrict__ AyT,
                                                  unsigned short* __restrict__ AxT) {
    int blk  = blockIdx.x;
    int r    = blk & 63;
    int axis = (blk >> 6) & 1;
    int b    = blk >> 7;

    const float* p = tp + b*6 + (axis ? 3 : 0);
    float u = p[0], s = p[1], d = p[2];
    float centre = u + (float)r * d;
    float inv_s  = 1.0f / s;

    int lane = threadIdx.x;
    float e[8];
    float sum = 0.0f;
    #pragma unroll
    for (int i = 0; i < 8; ++i) {
        float z = ((float)(i*64 + lane) - centre) * inv_s;
        e[i] = __expf(-0.5f * z * z);
        sum += e[i];
    }
    #pragma unroll
    for (int m = 1; m < 64; m <<= 1)
        sum += __shfl_xor(sum, m, 64);
    float inv_sum = 1.0f / (sum + 1e-8f);

    unsigned short* dst = (axis ? AxT : AyT) + ((size_t)b*GOUT + r) * IMG;
    #pragma unroll
    for (int i = 0; i < 8; ++i)
        dst[i*64 + lane] = f2bf(e[i] * inv_sum);
}

// ---------------------------------------------------------------------------
// Kernel 2: gP[part][b][c][H][w] = sum_{h in part} Ay[b,h,H]*img[b,h,w,c]
// Round-5 failure: 384 blocks = 1.5/CU -> 15% occupancy, latency-bound.
// Now: 64H x 64wc tile, BK=64, K-split 2 -> 1536 blocks, LDS 25.6 KB ->
// 6 blocks/CU = 24 waves/CU. Bs staged by global_load_lds width=16 (async,
// no VGPR round-trip); As (bf16, +8 pad) staged normally. 4 waves each own a
// 16-wc strip; 8 MFMA/chunk/wave.
// ---------------------------------------------------------------------------
__global__ __launch_bounds__(256, 6) void stage1_kernel(const float* __restrict__ img,
                                                        const unsigned short* __restrict__ AyT,
                                                        float* __restrict__ gP) {
    __shared__ float          Bs[64][64];   // img tile fp32, UNPADDED (async dest)
    __shared__ unsigned short As[64][72];   // Ay tile bf16, +8 pad

    int part = blockIdx.x & 1;
    int bt   = blockIdx.x >> 1;
    int tile = bt % 24;
    int b    = bt / 24;
    int wc0  = tile * 64;
    int tid  = threadIdx.x;
    int wave = tid >> 6;
    int lane = tid & 63;
    int n16  = lane & 15;
    int q    = lane >> 4;

    floatx4 acc[4];
    #pragma unroll
    for (int mt = 0; mt < 4; ++mt) acc[mt] = (floatx4){0.f, 0.f, 0.f, 0.f};

    const float*          imb = img + (size_t)b * IMG * ROWB + wc0;
    const unsigned short* ayb = AyT + (size_t)b * GOUT * IMG;

    int rb = (tid >> 6)*4 + ((tid & 63) >> 4);  // async row base (w*4 + l>>4)
    int cg = tid & 15;                          // float4 within row

    for (int h0 = part*256; h0 < part*256 + 256; h0 += 64) {
        // --- As loads first (so their waitcnt doesn't drain Bs queue) ---
        uint4 av[2];
        #pragma unroll
        for (int i = 0; i < 2; ++i) {
            int p = tid + i*256;
            av[i] = *(const uint4*)(ayb + (size_t)(p >> 3) * IMG + h0 + (p & 7)*8);
        }
        // --- Bs: async global->LDS, 4 instrs/wave, 1 KB contiguous each ---
        #pragma unroll
        for (int i = 0; i < 4; ++i) {
            int r = rb + i*16;
            async16(imb + (size_t)(h0 + r) * ROWB + cg*4, &Bs[r][cg*4]);
        }
        #pragma unroll
        for (int i = 0; i < 2; ++i) {
            int p = tid + i*256;
            *(uint4*)&As[p >> 3][(p & 7)*8] = av[i];
        }
        __syncthreads();   // drains vmcnt (incl. async) + lgkm

        #pragma unroll
        for (int s = 0; s < 2; ++s) {
            short8 bf;
            #pragma unroll
            for (int j = 0; j < 8; ++j)
                bf[j] = (short)f2bf(Bs[s*32 + q*8 + j][wave*16 + n16]);
            #pragma unroll
            for (int mt = 0; mt < 4; ++mt) {
                short8 af = *(const short8*)&As[mt*16 + n16][s*32 + q*8];
                acc[mt] = __builtin_amdgcn_mfma_f32_16x16x32_bf16(af, bf, acc[mt], 0, 0, 0);
            }
        }
        __syncthreads();
    }

    // Epilogue: D col = lane&15 -> wc, row = q*4+reg -> H (verified r4/r5).
    int wc = wc0 + wave*16 + n16;
    int c = wc % 3, w = wc / 3;
    float* gb = gP + (size_t)part * GP + ((size_t)(b*CH + c) * GOUT) * IMG + w;
    #pragma unroll
    for (int mt = 0; mt < 4; ++mt)
        #pragma unroll
        for (int reg = 0; reg < 4; ++reg)
            gb[(size_t)(mt*16 + q*4 + reg) * IMG] = acc[mt][reg];
}

// ---------------------------------------------------------------------------
// Kernel 3: out[b,H,W,c] += sum_{w part} (g0+g1)[b,c,H,w] * Ax[b,w,W]
// bf16 MFMA; grid (b,c,part)=384; K-split 4, fp32 atomicAdd into zeroed out.
// ---------------------------------------------------------------------------
__global__ __launch_bounds__(256) void stage2_kernel(const float* __restrict__ gP,
                                                     const unsigned short* __restrict__ AxT,
                                                     float* __restrict__ out) {
    int blk  = blockIdx.x;
    int part = blk & 3;
    int bc   = blk >> 2;
    int c    = bc % 3;
    int b    = bc / 3;
    int tid  = threadIdx.x;
    int wm   = tid >> 6;
    int lane = tid & 63;
    int n16  = lane & 15;
    int q    = lane >> 4;

    floatx4 acc[4];
    #pragma unroll
    for (int nt = 0; nt < 4; ++nt) acc[nt] = (floatx4){0.f, 0.f, 0.f, 0.f};

    const float*          ga  = gP  + ((size_t)(b*CH + c) * GOUT + wm*16 + n16) * IMG;
    const unsigned short* axb = AxT + ((size_t)b*GOUT + n16) * IMG;

    #pragma unroll
    for (int cc = 0; cc < 4; ++cc) {
        int w0 = part*128 + cc*32;
        const float* ap = ga + w0 + q*8;
        float4 a0 = *(const float4*)ap;
        float4 a1 = *(const float4*)(ap + 4);
        float4 b0 = *(const float4*)(ap + GP);
        float4 b1 = *(const float4*)(ap + GP + 4);
        short8 af;
        af[0] = (short)f2bf(a0.x + b0.x); af[1] = (short)f2bf(a0.y + b0.y);
        af[2] = (short)f2bf(a0.z + b0.z); af[3] = (short)f2bf(a0.w + b0.w);
        af[4] = (short)f2bf(a1.x + b1.x); af[5] = (short)f2bf(a1.y + b1.y);
        af[6] = (short)f2bf(a1.z + b1.z); af[7] = (short)f2bf(a1.w + b1.w);

        #pragma unroll
        for (int nt = 0; nt < 4; ++nt) {
            short8 bf = *(const short8*)(axb + (size_t)nt*16*IMG + w0 + q*8);
            acc[nt] = __builtin_amdgcn_mfma_f32_16x16x32_bf16(af, bf, acc[nt], 0, 0, 0);
        }
    }

    #pragma unroll
    for (int nt = 0; nt < 4; ++nt) {
        int W = nt*16 + n16;
        #pragma unroll
        for (int reg = 0; reg < 4; ++reg) {
            int H = wm*16 + q*4 + reg;
            atomicAdd(out + (((size_t)b*GOUT + H) * GOUT + W) * CH + c, acc[nt][reg]);
        }
    }
}

// ---------------------------------------------------------------------------
// Workspace: AyT 2 MB | AxT 2 MB | gP 2 x 12.6 MB  (~29 MB).
// ---------------------------------------------------------------------------
extern "C" void kernel_launch(void* const* d_in, const int* in_sizes, int n_in,
                              void* d_out, int out_size, void* d_ws, size_t ws_size,
                              hipStream_t stream) {
    const float* img = (const float*)d_in[0];
    const float* tp  = (const float*)d_in[1];
    float* out = (float*)d_out;

    unsigned short* AyT = (unsigned short*)d_ws;
    unsigned short* AxT = AyT + (size_t)BATCH * GOUT * IMG;
    float*          gPp = (float*)(AxT + (size_t)BATCH * GOUT * IMG);

    hipMemsetAsync(d_out, 0, (size_t)out_size * sizeof(float), stream);
    mask_kernel  <<<BATCH * 2 * GOUT,   64, 0, stream>>>(tp, AyT, AxT);
    stage1_kernel<<<BATCH * 24 * 2,    256, 0, stream>>>(img, AyT, gPp);
    stage2_kernel<<<BATCH * CH * 4,    256, 0, stream>>>(gPp, AxT, out);
}